// Round 4
// baseline (1127.572 us; speedup 1.0000x reference)
//
#include <hip/hip_runtime.h>
#include <hip/hip_bf16.h>
#include <stdint.h>

#define IN_CH 64
#define OUT_CH 128
#define EPB 128  // entries per block, phase 1

// ---------- fast path (contrib buffer + inverse rulebook) ----------

// Zero counts[n_out] and sums[256].
__global__ void __launch_bounds__(256) zero_meta_kernel(
    int* __restrict__ counts, int n_out, float* __restrict__ sums) {
    int i = blockIdx.x * 256 + threadIdx.x;
    if (i < n_out) counts[i] = 0;
    if (blockIdx.x == 0) sums[threadIdx.x] = 0.f;
}

// Block = 4 waves. Wave (k=blockIdx.y, half=waveId&1) streams entries
// r = r0+(waveId>>1), step 2. W columns live in 64 VGPRs, reused across
// entries; f row is wave-uniform (scalar loads). Plain store, no atomics.
__global__ void __launch_bounds__(256) contrib_kernel(
    const float* __restrict__ feats,
    const float* __restrict__ W,
    const int* __restrict__ in_idx,
    const int* __restrict__ mask,
    float* __restrict__ contrib,   // [9R, 128]
    int R)
{
    const int lane = threadIdx.x & 63;
    const int waveId = threadIdx.x >> 6;
    const int half = waveId & 1;
    const int pair = waveId >> 1;
    const int k = blockIdx.y;
    const int c = half * 64 + lane;

    float wreg[IN_CH];
    const float* __restrict__ wp = W + (size_t)k * IN_CH * OUT_CH + c;
#pragma unroll
    for (int i = 0; i < IN_CH; ++i) wreg[i] = wp[i * OUT_CH];

    const int r0 = blockIdx.x * EPB;
    const int rEnd = min(r0 + EPB, R);
    const int* __restrict__ maskK = mask + (size_t)k * R;
    const int* __restrict__ inK = in_idx + (size_t)k * R;

    for (int r = r0 + pair; r < rEnd; r += 2) {
        if (!__builtin_amdgcn_readfirstlane(maskK[r])) continue;
        int in = __builtin_amdgcn_readfirstlane(inK[r]);
        const float* __restrict__ f = feats + (size_t)in * IN_CH;
        float s = 0.f, s1 = 0.f;
#pragma unroll
        for (int i = 0; i < IN_CH; i += 2) {
            s = fmaf(wreg[i], f[i], s);
            s1 = fmaf(wreg[i + 1], f[i + 1], s1);
        }
        contrib[((size_t)k * R + r) * OUT_CH + c] = s + s1;
    }
}

// Inverse rulebook: for each valid entry, append its id to the out row's
// list (multiplicity <= 9, so fixed-width rows, no scan needed).
__global__ void __launch_bounds__(256) build_kernel(
    const int* __restrict__ out_idx,
    const int* __restrict__ mask,
    int* __restrict__ counts,
    int* __restrict__ list,   // [n_out, 9]
    int nE)
{
    int e = blockIdx.x * 256 + threadIdx.x;
    if (e >= nE || !mask[e]) return;
    int out = out_idx[e];
    int slot = atomicAdd(&counts[out], 1);
    list[(size_t)out * 9 + slot] = e;
}

// Gather-reduce contributions per out row (float4) + fused BN stats.
// Block = 256 threads = 8 row-slots x 32 channel-groups; 8 iterations
// -> 64 rows per block.
__global__ void __launch_bounds__(256) gather_stats_kernel(
    const float4* __restrict__ contrib4,   // [9R, 32]
    const int* __restrict__ counts,
    const int* __restrict__ list,
    float4* __restrict__ acc4,             // [n_out, 32]
    float* __restrict__ sums,              // [256]
    int n_out)
{
    const int c32 = threadIdx.x & 31;
    const int rslot = threadIdx.x >> 5;
    const int rbase = blockIdx.x * 64;

    float4 s = make_float4(0.f, 0.f, 0.f, 0.f);
    float4 s2 = make_float4(0.f, 0.f, 0.f, 0.f);

    for (int it = 0; it < 8; ++it) {
        int r = rbase + it * 8 + rslot;
        if (r >= n_out) continue;
        int cnt = counts[r];
        const int* __restrict__ lp = list + (size_t)r * 9;
        float4 v = make_float4(0.f, 0.f, 0.f, 0.f);
        for (int j = 0; j < cnt; ++j) {
            int eid = lp[j];
            float4 t = contrib4[(size_t)eid * 32 + c32];
            v.x += t.x; v.y += t.y; v.z += t.z; v.w += t.w;
        }
        acc4[(size_t)r * 32 + c32] = v;
        s.x += v.x; s.y += v.y; s.z += v.z; s.w += v.w;
        s2.x += v.x * v.x; s2.y += v.y * v.y; s2.z += v.z * v.z; s2.w += v.w * v.w;
    }

    __shared__ float4 redS[8][32];
    __shared__ float4 redS2[8][32];
    redS[rslot][c32] = s;
    redS2[rslot][c32] = s2;
    __syncthreads();
    if (threadIdx.x < 32) {
        float4 a = make_float4(0.f, 0.f, 0.f, 0.f);
        float4 b = make_float4(0.f, 0.f, 0.f, 0.f);
#pragma unroll
        for (int j = 0; j < 8; ++j) {
            float4 t = redS[j][threadIdx.x];
            a.x += t.x; a.y += t.y; a.z += t.z; a.w += t.w;
            float4 u = redS2[j][threadIdx.x];
            b.x += u.x; b.y += u.y; b.z += u.z; b.w += u.w;
        }
        int c0 = threadIdx.x * 4;
        atomicAdd(&sums[c0 + 0], a.x);
        atomicAdd(&sums[c0 + 1], a.y);
        atomicAdd(&sums[c0 + 2], a.z);
        atomicAdd(&sums[c0 + 3], a.w);
        atomicAdd(&sums[OUT_CH + c0 + 0], b.x);
        atomicAdd(&sums[OUT_CH + c0 + 1], b.y);
        atomicAdd(&sums[OUT_CH + c0 + 2], b.z);
        atomicAdd(&sums[OUT_CH + c0 + 3], b.w);
    }
}

// y = gamma*(x-mean)*rsqrt(var+eps)+beta, relu; in-place, float4.
__global__ void __launch_bounds__(256) bn_relu_kernel(
    float4* __restrict__ out,
    const float* __restrict__ sums,
    const float* __restrict__ gamma,
    const float* __restrict__ beta,
    int total4, float inv_n)
{
    int idx = blockIdx.x * 256 + threadIdx.x;
    if (idx >= total4) return;
    int c0 = (idx & 31) * 4;
    float4 v = out[idx];
    float r[4] = {v.x, v.y, v.z, v.w};
#pragma unroll
    for (int j = 0; j < 4; ++j) {
        int c = c0 + j;
        float mean = sums[c] * inv_n;
        float var = sums[OUT_CH + c] * inv_n - mean * mean;
        float scale = gamma[c] * rsqrtf(var + 1e-5f);
        float y = (r[j] - mean) * scale + beta[c];
        r[j] = fmaxf(y, 0.0f);
    }
    out[idx] = make_float4(r[0], r[1], r[2], r[3]);
}

// ---------- fallback path (round-3 atomic scatter), used if ws too small ----

__global__ void __launch_bounds__(256) zero_kernel(float4* __restrict__ out, int n4,
                                                   float* __restrict__ sums) {
    int idx = blockIdx.x * 256 + threadIdx.x;
    if (idx < n4) out[idx] = make_float4(0.f, 0.f, 0.f, 0.f);
    if (blockIdx.x == 0 && threadIdx.x < 2 * OUT_CH) sums[threadIdx.x] = 0.f;
}

__global__ void __launch_bounds__(256) scatter_gemm_kernel(
    const float* __restrict__ feats,
    const float* __restrict__ W,
    const int* __restrict__ in_idx,
    const int* __restrict__ out_idx,
    const int* __restrict__ mask,
    float* __restrict__ acc,
    int R)
{
    const int lane = threadIdx.x & 63;
    const int waveId = threadIdx.x >> 6;
    const int half = waveId & 1;
    const int pair = waveId >> 1;
    const int k = blockIdx.y;
    const int c = half * 64 + lane;

    float wreg[IN_CH];
    const float* __restrict__ wp = W + (size_t)k * IN_CH * OUT_CH + c;
#pragma unroll
    for (int i = 0; i < IN_CH; ++i) wreg[i] = wp[i * OUT_CH];

    const int r0 = blockIdx.x * EPB;
    const int rEnd = min(r0 + EPB, R);
    const int* __restrict__ maskK = mask + (size_t)k * R;
    const int* __restrict__ inK = in_idx + (size_t)k * R;
    const int* __restrict__ outK = out_idx + (size_t)k * R;

    for (int r = r0 + pair; r < rEnd; r += 2) {
        if (!__builtin_amdgcn_readfirstlane(maskK[r])) continue;
        int in = __builtin_amdgcn_readfirstlane(inK[r]);
        int out = __builtin_amdgcn_readfirstlane(outK[r]);
        const float* __restrict__ f = feats + (size_t)in * IN_CH;
        float s = 0.f, s1 = 0.f;
#pragma unroll
        for (int i = 0; i < IN_CH; i += 2) {
            s = fmaf(wreg[i], f[i], s);
            s1 = fmaf(wreg[i + 1], f[i + 1], s1);
        }
        atomicAdd(acc + (size_t)out * OUT_CH + c, s + s1);
    }
}

__global__ void __launch_bounds__(128) stats_kernel(
    const float* __restrict__ acc,
    float* __restrict__ sums,
    int n_out)
{
    int c = threadIdx.x;
    float s = 0.0f, s2 = 0.0f;
    for (int r = blockIdx.x; r < n_out; r += gridDim.x) {
        float v = acc[(size_t)r * OUT_CH + c];
        s += v;
        s2 += v * v;
    }
    atomicAdd(&sums[c], s);
    atomicAdd(&sums[OUT_CH + c], s2);
}

// ---------- launch ----------

extern "C" void kernel_launch(void* const* d_in, const int* in_sizes, int n_in,
                              void* d_out, int out_size, void* d_ws, size_t ws_size,
                              hipStream_t stream) {
    const float* feats   = (const float*)d_in[0];
    const float* W       = (const float*)d_in[1];
    const float* gamma   = (const float*)d_in[2];
    const float* beta    = (const float*)d_in[3];
    const int*   in_idx  = (const int*)d_in[4];
    const int*   out_idx = (const int*)d_in[5];
    const int*   mask    = (const int*)d_in[6];   // bool stored as int32

    const int R = in_sizes[4] / 9;
    const int nE = 9 * R;
    const int n_out = out_size / OUT_CH;
    float* acc = (float*)d_out;

    // ws layout for fast path
    size_t off_contrib = 0;
    size_t sz_contrib = (size_t)nE * OUT_CH * sizeof(float);
    size_t off_counts = off_contrib + sz_contrib;
    size_t off_list = (off_counts + (size_t)n_out * 4 + 15) & ~(size_t)15;
    size_t off_sums = (off_list + (size_t)n_out * 9 * 4 + 15) & ~(size_t)15;
    size_t needed = off_sums + 1024;

    if (ws_size >= needed) {
        float* contrib = (float*)((char*)d_ws + off_contrib);
        int*   counts  = (int*)((char*)d_ws + off_counts);
        int*   list    = (int*)((char*)d_ws + off_list);
        float* sums    = (float*)((char*)d_ws + off_sums);

        zero_meta_kernel<<<(n_out + 255) / 256, 256, 0, stream>>>(counts, n_out, sums);

        dim3 grid1((R + EPB - 1) / EPB, 9);
        contrib_kernel<<<grid1, 256, 0, stream>>>(feats, W, in_idx, mask, contrib, R);

        build_kernel<<<(nE + 255) / 256, 256, 0, stream>>>(out_idx, mask, counts, list, nE);

        int blocks2 = (n_out + 63) / 64;
        gather_stats_kernel<<<blocks2, 256, 0, stream>>>(
            (const float4*)contrib, counts, list, (float4*)acc, sums, n_out);

        int total4 = out_size / 4;
        bn_relu_kernel<<<(total4 + 255) / 256, 256, 0, stream>>>(
            (float4*)acc, sums, gamma, beta, total4, 1.0f / (float)n_out);
    } else {
        // fallback: atomic scatter path (round-3)
        float* sums = (float*)d_ws;
        int n4 = out_size / 4;
        zero_kernel<<<(n4 + 255) / 256, 256, 0, stream>>>((float4*)acc, n4, sums);

        dim3 grid((R + EPB - 1) / EPB, 9);
        scatter_gemm_kernel<<<grid, 256, 0, stream>>>(feats, W, in_idx, out_idx, mask, acc, R);

        stats_kernel<<<2048, 128, 0, stream>>>(acc, sums, n_out);

        int total4 = out_size / 4;
        bn_relu_kernel<<<(total4 + 255) / 256, 256, 0, stream>>>(
            (float4*)acc, sums, gamma, beta, total4, 1.0f / (float)n_out);
    }
}

// Round 5
// 675.848 us; speedup vs baseline: 1.6684x; 1.6684x over previous
//
#include <hip/hip_runtime.h>
#include <hip/hip_bf16.h>
#include <stdint.h>

#define IN_CH 64
#define OUT_CH 128
#define EPB 128     // entries per block (phase 1); 2 pair-strips of 64
#define GS_RPB 64   // rows per block (gather); 4 waves x 16 iterations

// Zero counts[n_out] and sums[256].
__global__ void __launch_bounds__(256) zero_meta_kernel(
    int* __restrict__ counts, int n_out, float* __restrict__ sums) {
    int i = blockIdx.x * 256 + threadIdx.x;
    if (i < n_out) counts[i] = 0;
    if (blockIdx.x == 0) sums[threadIdx.x] = 0.f;
}

// Phase 1: per-entry matvec into contrib[9R,128]. Wave = (k, half) with the
// 64 W columns in VGPRs; contiguous 64-entry strip per wave-pair; mask/in
// batch-prefetched 8 entries ahead into SGPRs so the only per-entry latency
// is the f-row scalar load, overlapped with the previous entry's fmas.
__global__ void __launch_bounds__(256) contrib_kernel(
    const float* __restrict__ feats,
    const float* __restrict__ W,
    const int* __restrict__ in_idx,
    const int* __restrict__ mask,
    float* __restrict__ contrib,   // [9R, 128]
    int R)
{
    const int lane = threadIdx.x & 63;
    const int half = __builtin_amdgcn_readfirstlane((threadIdx.x >> 6) & 1);
    const int pair = __builtin_amdgcn_readfirstlane(threadIdx.x >> 7);
    const int k = blockIdx.y;
    const int c = half * 64 + lane;

    float wreg[IN_CH];
    const float* __restrict__ wp = W + (size_t)k * IN_CH * OUT_CH + c;
#pragma unroll
    for (int i = 0; i < IN_CH; ++i) wreg[i] = wp[i * OUT_CH];

    const int r0 = blockIdx.x * EPB + pair * 64;
    if (r0 >= R) return;
    const int rEnd = min(r0 + 64, R);
    const int* __restrict__ maskK = mask + (size_t)k * R;
    const int* __restrict__ inK  = in_idx + (size_t)k * R;
    float* __restrict__ outBase = contrib + (size_t)k * R * OUT_CH + c;

    for (int rb = r0; rb < rEnd; rb += 8) {
        const int nchunk = min(8, rEnd - rb);
        int m8[8], in8[8];
#pragma unroll
        for (int j = 0; j < 8; ++j) {
            int rr = (rb + j < rEnd) ? rb + j : rEnd - 1;  // clamp (stay in row k)
            m8[j]  = __builtin_amdgcn_readfirstlane(maskK[rr]);
            in8[j] = __builtin_amdgcn_readfirstlane(inK[rr]);
        }
#pragma unroll
        for (int j = 0; j < 8; ++j) {
            if (j >= nchunk) break;
            if (!m8[j]) continue;
            const float* __restrict__ f = feats + (size_t)in8[j] * IN_CH;
            float s = 0.f, s1 = 0.f;
#pragma unroll
            for (int i = 0; i < IN_CH; i += 2) {
                s  = fmaf(wreg[i],     f[i],     s);
                s1 = fmaf(wreg[i + 1], f[i + 1], s1);
            }
            outBase[(size_t)(rb + j) * OUT_CH] = s + s1;
        }
    }
}

// Inverse rulebook: append entry id to its out row's fixed-width list.
__global__ void __launch_bounds__(256) build_kernel(
    const int* __restrict__ out_idx,
    const int* __restrict__ mask,
    int* __restrict__ counts,
    int* __restrict__ list,   // [n_out, 9]
    int nE)
{
    int e = blockIdx.x * 256 + threadIdx.x;
    if (e >= nE || !mask[e]) return;
    int out = out_idx[e];
    int slot = atomicAdd(&counts[out], 1);
    list[(size_t)out * 9 + slot] = e;
}

// Phase 2: one wave per row (uniform row index -> scalar meta loads).
// All 9 list slots loaded unconditionally+independently; contrib loads
// issued independently under uniform branches. Fused BN stats.
__global__ void __launch_bounds__(256) gather_stats_kernel(
    const float2* __restrict__ contrib2,   // [9R, 64]
    const int* __restrict__ counts,
    const int* __restrict__ list,
    float2* __restrict__ acc2,             // [n_out, 64]
    float* __restrict__ sums,              // [256]
    int n_out)
{
    const int lane = threadIdx.x & 63;
    const int w = __builtin_amdgcn_readfirstlane(threadIdx.x >> 6);
    const int rbase = blockIdx.x * GS_RPB;

    float sx = 0.f, sy = 0.f, qx = 0.f, qy = 0.f;

#pragma unroll 2
    for (int it = 0; it < GS_RPB / 4; ++it) {
        int r = rbase + it * 4 + w;
        if (r < n_out) {
            int cnt = __builtin_amdgcn_readfirstlane(counts[r]);
            const int* __restrict__ lp = list + (size_t)r * 9;
            int e[9];
#pragma unroll
            for (int j = 0; j < 9; ++j)
                e[j] = __builtin_amdgcn_readfirstlane(lp[j]);
            float vx = 0.f, vy = 0.f;
#pragma unroll
            for (int j = 0; j < 9; ++j) {
                if (j < cnt) {   // wave-uniform branch
                    float2 t = contrib2[(size_t)e[j] * 64 + lane];
                    vx += t.x; vy += t.y;
                }
            }
            acc2[(size_t)r * 64 + lane] = make_float2(vx, vy);
            sx += vx; sy += vy; qx += vx * vx; qy += vy * vy;
        }
    }

    __shared__ float redS[4][128];
    __shared__ float redQ[4][128];
    redS[w][lane * 2] = sx;  redS[w][lane * 2 + 1] = sy;
    redQ[w][lane * 2] = qx;  redQ[w][lane * 2 + 1] = qy;
    __syncthreads();
    if (threadIdx.x < 128) {
        int cch = threadIdx.x;
        float a = redS[0][cch] + redS[1][cch] + redS[2][cch] + redS[3][cch];
        float b = redQ[0][cch] + redQ[1][cch] + redQ[2][cch] + redQ[3][cch];
        atomicAdd(&sums[cch], a);
        atomicAdd(&sums[OUT_CH + cch], b);
    }
}

// y = gamma*(x-mean)*rsqrt(var+eps)+beta, relu; in-place, float4.
__global__ void __launch_bounds__(256) bn_relu_kernel(
    float4* __restrict__ out,
    const float* __restrict__ sums,
    const float* __restrict__ gamma,
    const float* __restrict__ beta,
    int total4, float inv_n)
{
    int idx = blockIdx.x * 256 + threadIdx.x;
    if (idx >= total4) return;
    int c0 = (idx & 31) * 4;
    float4 v = out[idx];
    float r[4] = {v.x, v.y, v.z, v.w};
#pragma unroll
    for (int j = 0; j < 4; ++j) {
        int c = c0 + j;
        float mean = sums[c] * inv_n;
        float var = sums[OUT_CH + c] * inv_n - mean * mean;
        float scale = gamma[c] * rsqrtf(var + 1e-5f);
        float y = (r[j] - mean) * scale + beta[c];
        r[j] = fmaxf(y, 0.0f);
    }
    out[idx] = make_float4(r[0], r[1], r[2], r[3]);
}

// ---------- fallback (atomic scatter, round-3) if ws too small ----------

__global__ void __launch_bounds__(256) zero_kernel(float4* __restrict__ out, int n4,
                                                   float* __restrict__ sums) {
    int idx = blockIdx.x * 256 + threadIdx.x;
    if (idx < n4) out[idx] = make_float4(0.f, 0.f, 0.f, 0.f);
    if (blockIdx.x == 0 && threadIdx.x < 2 * OUT_CH) sums[threadIdx.x] = 0.f;
}

__global__ void __launch_bounds__(256) scatter_gemm_kernel(
    const float* __restrict__ feats,
    const float* __restrict__ W,
    const int* __restrict__ in_idx,
    const int* __restrict__ out_idx,
    const int* __restrict__ mask,
    float* __restrict__ acc,
    int R)
{
    const int lane = threadIdx.x & 63;
    const int waveId = threadIdx.x >> 6;
    const int half = waveId & 1;
    const int pair = waveId >> 1;
    const int k = blockIdx.y;
    const int c = half * 64 + lane;

    float wreg[IN_CH];
    const float* __restrict__ wp = W + (size_t)k * IN_CH * OUT_CH + c;
#pragma unroll
    for (int i = 0; i < IN_CH; ++i) wreg[i] = wp[i * OUT_CH];

    const int r0 = blockIdx.x * EPB;
    const int rEnd = min(r0 + EPB, R);
    const int* __restrict__ maskK = mask + (size_t)k * R;
    const int* __restrict__ inK = in_idx + (size_t)k * R;
    const int* __restrict__ outK = out_idx + (size_t)k * R;

    for (int r = r0 + pair; r < rEnd; r += 2) {
        if (!__builtin_amdgcn_readfirstlane(maskK[r])) continue;
        int in = __builtin_amdgcn_readfirstlane(inK[r]);
        int out = __builtin_amdgcn_readfirstlane(outK[r]);
        const float* __restrict__ f = feats + (size_t)in * IN_CH;
        float s = 0.f, s1 = 0.f;
#pragma unroll
        for (int i = 0; i < IN_CH; i += 2) {
            s = fmaf(wreg[i], f[i], s);
            s1 = fmaf(wreg[i + 1], f[i + 1], s1);
        }
        atomicAdd(acc + (size_t)out * OUT_CH + c, s + s1);
    }
}

__global__ void __launch_bounds__(128) stats_kernel(
    const float* __restrict__ acc,
    float* __restrict__ sums,
    int n_out)
{
    int c = threadIdx.x;
    float s = 0.0f, s2 = 0.0f;
    for (int r = blockIdx.x; r < n_out; r += gridDim.x) {
        float v = acc[(size_t)r * OUT_CH + c];
        s += v;
        s2 += v * v;
    }
    atomicAdd(&sums[c], s);
    atomicAdd(&sums[OUT_CH + c], s2);
}

// ---------- launch ----------

extern "C" void kernel_launch(void* const* d_in, const int* in_sizes, int n_in,
                              void* d_out, int out_size, void* d_ws, size_t ws_size,
                              hipStream_t stream) {
    const float* feats   = (const float*)d_in[0];
    const float* W       = (const float*)d_in[1];
    const float* gamma   = (const float*)d_in[2];
    const float* beta    = (const float*)d_in[3];
    const int*   in_idx  = (const int*)d_in[4];
    const int*   out_idx = (const int*)d_in[5];
    const int*   mask    = (const int*)d_in[6];   // bool stored as int32

    const int R = in_sizes[4] / 9;
    const int nE = 9 * R;
    const int n_out = out_size / OUT_CH;
    float* acc = (float*)d_out;

    size_t off_contrib = 0;
    size_t sz_contrib = (size_t)nE * OUT_CH * sizeof(float);
    size_t off_counts = off_contrib + sz_contrib;
    size_t off_list = (off_counts + (size_t)n_out * 4 + 15) & ~(size_t)15;
    size_t off_sums = (off_list + (size_t)n_out * 9 * 4 + 15) & ~(size_t)15;
    size_t needed = off_sums + 1024;

    if (ws_size >= needed) {
        float* contrib = (float*)((char*)d_ws + off_contrib);
        int*   counts  = (int*)((char*)d_ws + off_counts);
        int*   list    = (int*)((char*)d_ws + off_list);
        float* sums    = (float*)((char*)d_ws + off_sums);

        zero_meta_kernel<<<(n_out + 255) / 256, 256, 0, stream>>>(counts, n_out, sums);

        dim3 grid1((R + EPB - 1) / EPB, 9);
        contrib_kernel<<<grid1, 256, 0, stream>>>(feats, W, in_idx, mask, contrib, R);

        build_kernel<<<(nE + 255) / 256, 256, 0, stream>>>(out_idx, mask, counts, list, nE);

        int blocks2 = (n_out + GS_RPB - 1) / GS_RPB;
        gather_stats_kernel<<<blocks2, 256, 0, stream>>>(
            (const float2*)contrib, counts, list, (float2*)acc, sums, n_out);

        int total4 = out_size / 4;
        bn_relu_kernel<<<(total4 + 255) / 256, 256, 0, stream>>>(
            (float4*)acc, sums, gamma, beta, total4, 1.0f / (float)n_out);
    } else {
        float* sums = (float*)d_ws;
        int n4 = out_size / 4;
        zero_kernel<<<(n4 + 255) / 256, 256, 0, stream>>>((float4*)acc, n4, sums);

        dim3 grid((R + EPB - 1) / EPB, 9);
        scatter_gemm_kernel<<<grid, 256, 0, stream>>>(feats, W, in_idx, out_idx, mask, acc, R);

        stats_kernel<<<2048, 128, 0, stream>>>(acc, sums, n_out);

        int total4 = out_size / 4;
        bn_relu_kernel<<<(total4 + 255) / 256, 256, 0, stream>>>(
            (float4*)acc, sums, gamma, beta, total4, 1.0f / (float)n_out);
    }
}